// Round 4
// baseline (668.865 us; speedup 1.0000x reference)
//
#include <hip/hip_runtime.h>
#include <stdint.h>

#define BB 2048
#define TT 200
#define DD 64
#define FF 256   // 4*D
#define H1C 256
#define H2C 128
#define H3C 64

typedef __bf16 bf16x8 __attribute__((ext_vector_type(8)));
typedef float floatx16 __attribute__((ext_vector_type(16)));
typedef float f32x4 __attribute__((ext_vector_type(4)));
typedef uint32_t u32x4 __attribute__((ext_vector_type(4)));
typedef uint32_t u32x2 __attribute__((ext_vector_type(2)));
typedef unsigned short u16;
typedef u16 u16x8 __attribute__((ext_vector_type(8)));

__device__ inline u16 f2bf(float f) {
    uint32_t u = __builtin_bit_cast(uint32_t, f) + 0x8000u;
    return (u16)(u >> 16);
}
__device__ inline float bf2f(u16 h) {
    uint32_t u = ((uint32_t)h) << 16;
    return __builtin_bit_cast(float, u);
}
// pack two floats -> bf16x2 (lo in low half): 2 adds + 1 v_perm_b32
__device__ inline uint32_t pkbf(float lo, float hi) {
    uint32_t ul = __builtin_bit_cast(uint32_t, lo) + 0x8000u;
    uint32_t uh = __builtin_bit_cast(uint32_t, hi) + 0x8000u;
    return __builtin_amdgcn_perm(uh, ul, 0x07060302);
}

// ---- weight pack: W[K][N] fp32 -> bf16 fragments. Element-identical for
// "B-frag of W" and "A-frag of W^T", so usable directly as the A operand.
template<int K, int N>
__device__ inline void pack_w_dev(const float* __restrict__ W, u16* __restrict__ out, int blk) {
    constexpr int NC = K / 16;
    int idx = blk * 256 + threadIdx.x;
    int j    = idx & 7;
    int lane = (idx >> 3) & 63;
    int rest = idx >> 9;
    int c  = rest % NC;
    int mt = rest / NC;
    int k = c * 16 + ((lane >> 5) << 3) + j;
    int n = mt * 32 + (lane & 31);
    out[idx] = f2bf(W[k * N + n]);
}
// ---- alpha pack: alpha[T][N] -> bf16 in transposed-C/D epilogue order:
// lane -> t = g.. , regs -> n. out[(((mb*2+tt)*MTOT+mt)*64+lane)*16+reg]
template<int NTOT>
__device__ inline void pack_a_dev(const float* __restrict__ A, u16* __restrict__ out, int blk) {
    constexpr int MTOT = NTOT / 32;
    int idx = blk * 256 + threadIdx.x;
    int reg  = idx & 15;
    int lane = (idx >> 4) & 63;
    int rest = idx >> 10;                 // (mb*2+tt)*MTOT + mt
    int mt = rest % MTOT;
    int g  = rest / MTOT;                 // 0..7
    int t  = (g >> 1) * 64 + (g & 1) * 32 + (lane & 31);
    int n  = mt * 32 + (reg & 3) + ((reg >> 2) << 3) + ((lane >> 5) << 2);
    out[idx] = (t < TT) ? f2bf(A[t * NTOT + n]) : (u16)0;
}

__global__ void pack_all(const float* __restrict__ W1, const float* __restrict__ W2,
                         const float* __restrict__ W3, const float* __restrict__ a1,
                         const float* __restrict__ a2, const float* __restrict__ a3,
                         u16* W1p, u16* W2p, u16* W3p, u16* A1p, u16* A2p, u16* A3p) {
    int blk = blockIdx.x;
    if      (blk < 256) pack_w_dev<FF, H1C>(W1, W1p, blk);
    else if (blk < 384) pack_w_dev<H1C, H2C>(W2, W2p, blk - 256);
    else if (blk < 416) pack_w_dev<H2C, H3C>(W3, W3p, blk - 384);
    else if (blk < 672) pack_a_dev<H1C>(a1, A1p, blk - 416);
    else if (blk < 800) pack_a_dev<H2C>(a2, A2p, blk - 672);
    else                pack_a_dev<H3C>(a3, A3p, blk - 800);
}

// One layer, transposed: D[m=n_out][n=t] = sum_k W^T[m][k] * X^T[k][t].
// A (weights) streamed from L2; B (activations) b128 from LDS; epilogue
// writes 4 consecutive n per reg-quad -> packed ds_write_b64.
// Xb: LDS base so that element [t][k] = Xb + t*IN_S + k.
// Y : LDS base so that h[t][n] = Y + t*OUT_S + n (caller folds col offset).
template<int NC, int NTOT, int IN_S, int OUT_S, int TTN>
__device__ __attribute__((always_inline)) inline
void layer_t(const u16* Xb, u16* Y, const u16* __restrict__ Wp,
             const float* __restrict__ bias, const u16* __restrict__ Ap,
             int mt, int tt0, int lane, int mb) {
    constexpr int MTOT = NTOT / 32;
    const int tl   = lane & 31;
    const int kq   = (lane >> 5) << 3;
    const int hsel = (lane >> 5) << 2;

    // weight A-fragments (L2-hot)
    bf16x8 wf[NC];
    const u16* wp = Wp + ((size_t)(mt * NC) * 64 + lane) * 8;
#pragma unroll
    for (int c = 0; c < NC; ++c)
        wf[c] = *reinterpret_cast<const bf16x8*>(wp + (size_t)c * 512);

    // bias pre-added into acc (per-reg n index)
    float bq[16];
#pragma unroll
    for (int q = 0; q < 4; ++q) {
        f32x4 bv = *reinterpret_cast<const f32x4*>(bias + mt * 32 + q * 8 + hsel);
#pragma unroll
        for (int i = 0; i < 4; ++i) bq[q * 4 + i] = bv[i];
    }
    floatx16 acc[TTN];
#pragma unroll
    for (int t = 0; t < TTN; ++t)
#pragma unroll
        for (int i = 0; i < 16; ++i) acc[t][i] = bq[i];

#pragma unroll
    for (int c = 0; c < NC; ++c) {
#pragma unroll
        for (int t = 0; t < TTN; ++t) {
            bf16x8 bfr = *reinterpret_cast<const bf16x8*>(
                Xb + ((tt0 + t) * 32 + tl) * IN_S + c * 16 + kq);
            acc[t] = __builtin_amdgcn_mfma_f32_32x32x16_bf16(wf[c], bfr, acc[t], 0, 0, 0);
        }
    }

#pragma unroll
    for (int t = 0; t < TTN; ++t) {
        const int tt = tt0 + t;
        const u16* ap = Ap + (((size_t)((mb * 2 + tt) * MTOT + mt) * 64 + lane) << 4);
        u16x8 av0 = *reinterpret_cast<const u16x8*>(ap);
        u16x8 av1 = *reinterpret_cast<const u16x8*>(ap + 8);
        const int row = tt * 32 + tl;
        u16* yrow = Y + row * OUT_S + mt * 32 + hsel;
#pragma unroll
        for (int q = 0; q < 4; ++q) {
            float p[4];
#pragma unroll
            for (int i = 0; i < 4; ++i) {
                const int r = q * 4 + i;
                float v = acc[t][r];
                float al = bf2f(r < 8 ? av0[r] : av1[r - 8]);
                p[i] = fmaxf(v, 0.f) + al * fminf(v, 0.f);   // PReLU
            }
            u32x2 pw = { pkbf(p[0], p[1]), pkbf(p[2], p[3]) };
            *reinterpret_cast<u32x2*>(yrow + q * 8) = pw;
        }
    }
}

__device__ inline void load_k(const float* __restrict__ Kin, int b, int t, int c0,
                              f32x4& a, f32x4& c) {
    if (t < TT) {
        const f32x4* p = reinterpret_cast<const f32x4*>(Kin + ((size_t)b * TT + t) * DD + c0);
        a = __builtin_nontemporal_load(p);
        c = __builtin_nontemporal_load(p + 1);
    } else {
        a = f32x4{0.f, 0.f, 0.f, 0.f};
        c = f32x4{0.f, 0.f, 0.f, 0.f};
    }
}

__global__ __launch_bounds__(512, 4)
void attn_pool_kernel(const float* __restrict__ Q, const float* __restrict__ Kin,
                      const u16* __restrict__ W1p, const float* __restrict__ b1,
                      const u16* __restrict__ A1p,
                      const u16* __restrict__ W2p, const float* __restrict__ b2,
                      const u16* __restrict__ A2p,
                      const u16* __restrict__ W3p, const float* __restrict__ b3,
                      const u16* __restrict__ A3p,
                      const float* __restrict__ Wl, const float* __restrict__ bl,
                      float* __restrict__ Out) {
    // att columns: [0:64)=q (later h3), [64:128)=k (kept for pooling!),
    //              [128:256)=q-k,q*k (later h2). h1s: h1. Total ~70 KB -> 2 blocks/CU.
    __shared__ __align__(16) u16 att[64 * 264];
    __shared__ __align__(16) u16 h1s[64 * 264];
    __shared__ float q_sh[64];
    __shared__ float k0_sh[64];
    __shared__ float pool_red[8][64];

    const int tid  = threadIdx.x;
    const int lane = tid & 63;
    const int w    = tid >> 6;          // 0..7
    const int b    = blockIdx.x;
    const int r    = tid >> 3;          // staging row 0..63
    const int c0   = (tid & 7) << 3;    // staging col group

    if (tid < 16) {
        reinterpret_cast<f32x4*>(q_sh)[tid] =
            reinterpret_cast<const f32x4*>(Q + (size_t)b * DD)[tid];
    }
    const float bl0 = bl[0];

    f32x4 kc0, kc1, kn0, kn1;
    load_k(Kin, b, r, c0, kc0, kc1);
    __syncthreads();                    // q_sh ready

    float pacc = 0.f;

#pragma unroll 1
    for (int mb = 0; mb < 4; ++mb) {
        const int t0 = mb * 64;

        // ---- stage att_in = [q | k | q-k | q*k] bf16 from registers
        {
            u16* attrow = att + r * 264;
            const f32x4 q0 = *reinterpret_cast<const f32x4*>(&q_sh[c0]);
            const f32x4 q1 = *reinterpret_cast<const f32x4*>(&q_sh[c0 + 4]);
            u32x4 uq = { pkbf(q0[0], q0[1]), pkbf(q0[2], q0[3]),
                         pkbf(q1[0], q1[1]), pkbf(q1[2], q1[3]) };
            u32x4 uk = { pkbf(kc0[0], kc0[1]), pkbf(kc0[2], kc0[3]),
                         pkbf(kc1[0], kc1[1]), pkbf(kc1[2], kc1[3]) };
            u32x4 ud = { pkbf(q0[0] - kc0[0], q0[1] - kc0[1]),
                         pkbf(q0[2] - kc0[2], q0[3] - kc0[3]),
                         pkbf(q1[0] - kc1[0], q1[1] - kc1[1]),
                         pkbf(q1[2] - kc1[2], q1[3] - kc1[3]) };
            u32x4 up = { pkbf(q0[0] * kc0[0], q0[1] * kc0[1]),
                         pkbf(q0[2] * kc0[2], q0[3] * kc0[3]),
                         pkbf(q1[0] * kc1[0], q1[1] * kc1[1]),
                         pkbf(q1[2] * kc1[2], q1[3] * kc1[3]) };
            *reinterpret_cast<u32x4*>(attrow + c0)       = uq;
            *reinterpret_cast<u32x4*>(attrow + 64 + c0)  = uk;
            *reinterpret_cast<u32x4*>(attrow + 128 + c0) = ud;
            *reinterpret_cast<u32x4*>(attrow + 192 + c0) = up;
            if (c0 == 0) k0_sh[r] = kc0[0];
        }
        // prefetch next mb's k while this mb computes
        if (mb < 3) load_k(Kin, b, t0 + 64 + r, c0, kn0, kn1);
        __syncthreads();                                            // (1) att ready

        // ---- layer1: h1[t][n1] (n1-tile = w, both t-tiles) -> h1s
        layer_t<16, H1C, 264, 264, 2>(att, h1s, W1p, b1, A1p, w, 0, lane, mb);
        __syncthreads();                                            // (2) h1 ready

        // ---- layer2: h2 -> att cols 128..255 (over dead q-k / q*k sections)
        layer_t<16, H2C, 264, 264, 1>(h1s, att + 128, W2p, b2, A2p, w & 3, w >> 2, lane, mb);
        __syncthreads();                                            // (3) h2 ready

        // ---- layer3: reads att cols 128.., writes h3 -> att cols 0..63 (dead q)
        if (w < 4)
            layer_t<8, H3C, 264, 264, 1>(att + 128, att, W3p, b3, A3p, w & 1, w >> 1, lane, mb);
        __syncthreads();                                            // (4) h3 ready

        // ---- score (wave-local rows) + pooling, no intermediate barrier
        {
            const int sm = tid >> 3;          // row 8w .. 8w+7 for this wave
            const int p  = tid & 7;
            u16x8 hv = *reinterpret_cast<const u16x8*>(att + sm * 264 + p * 8);
            const f32x4 wl0 = *reinterpret_cast<const f32x4*>(Wl + p * 8);
            const f32x4 wl1 = *reinterpret_cast<const f32x4*>(Wl + p * 8 + 4);
            float s = 0.f;
#pragma unroll
            for (int i = 0; i < 4; ++i) s += bf2f(hv[i]) * wl0[i];
#pragma unroll
            for (int i = 0; i < 4; ++i) s += bf2f(hv[4 + i]) * wl1[i];
            s += __shfl_xor(s, 1);
            s += __shfl_xor(s, 2);
            s += __shfl_xor(s, 4);            // all 8 lanes of group hold row-sum
            const int t = t0 + sm;
            float sc = s + bl0;
            if (t >= TT || k0_sh[sm] == 0.f) sc = 0.f;
            // pooling: wave w owns rows 8w..8w+7; k is att cols 64..127
#pragma unroll
            for (int i = 0; i < 8; ++i) {
                float si = __shfl(sc, 8 * i);
                pacc += si * bf2f(att[(w * 8 + i) * 264 + 64 + lane]);
            }
        }
        __syncthreads();                                            // (5) att reusable
        kc0 = kn0; kc1 = kn1;
    }

    pool_red[w][lane] = pacc;
    __syncthreads();
    if (tid < 64) {
        float s = 0.f;
#pragma unroll
        for (int i = 0; i < 8; ++i) s += pool_red[i][tid];
        Out[(size_t)b * DD + tid] = s;
    }
}

extern "C" void kernel_launch(void* const* d_in, const int* in_sizes, int n_in,
                              void* d_out, int out_size, void* d_ws, size_t ws_size,
                              hipStream_t stream) {
    (void)in_sizes; (void)n_in; (void)out_size; (void)ws_size;
    const float* Q  = (const float*)d_in[0];
    const float* Kk = (const float*)d_in[1];
    const float* W1 = (const float*)d_in[2];
    const float* b1 = (const float*)d_in[3];
    const float* a1 = (const float*)d_in[4];
    const float* W2 = (const float*)d_in[5];
    const float* b2 = (const float*)d_in[6];
    const float* a2 = (const float*)d_in[7];
    const float* W3 = (const float*)d_in[8];
    const float* b3 = (const float*)d_in[9];
    const float* a3 = (const float*)d_in[10];
    const float* Wl = (const float*)d_in[11];
    const float* bl = (const float*)d_in[12];
    float* Out = (float*)d_out;

    u16* ws  = (u16*)d_ws;
    u16* W1p = ws;                         // 65536 bf16
    u16* W2p = W1p + 65536;                // 32768
    u16* W3p = W2p + 32768;                //  8192
    u16* A1p = W3p + 8192;                 // 65536
    u16* A2p = A1p + 65536;                // 32768
    u16* A3p = A2p + 32768;                // 16384

    hipLaunchKernelGGL(pack_all, dim3(864), dim3(256), 0, stream,
                       W1, W2, W3, a1, a2, a3, W1p, W2p, W3p, A1p, A2p, A3p);
    hipLaunchKernelGGL(attn_pool_kernel, dim3(BB), dim3(512), 0, stream,
                       Q, Kk, W1p, b1, A1p, W2p, b2, A2p, W3p, b3, A3p, Wl, bl, Out);
}

// Round 5
// 493.301 us; speedup vs baseline: 1.3559x; 1.3559x over previous
//
#include <hip/hip_runtime.h>
#include <stdint.h>

#define BB 2048
#define TT 200
#define DD 64
#define FF 256   // 4*D
#define H1C 256
#define H2C 128
#define H3C 64

typedef __bf16 bf16x8 __attribute__((ext_vector_type(8)));
typedef float floatx16 __attribute__((ext_vector_type(16)));
typedef float f32x4 __attribute__((ext_vector_type(4)));
typedef uint32_t u32x4 __attribute__((ext_vector_type(4)));
typedef uint32_t u32x2 __attribute__((ext_vector_type(2)));
typedef unsigned short u16;
typedef u16 u16x8 __attribute__((ext_vector_type(8)));

__device__ inline u16 f2bf(float f) {
    uint32_t u = __builtin_bit_cast(uint32_t, f) + 0x8000u;
    return (u16)(u >> 16);
}
__device__ inline float bf2f(u16 h) {
    uint32_t u = ((uint32_t)h) << 16;
    return __builtin_bit_cast(float, u);
}
__device__ inline uint32_t pkbf(float lo, float hi) {
    uint32_t ul = __builtin_bit_cast(uint32_t, lo) + 0x8000u;
    uint32_t uh = __builtin_bit_cast(uint32_t, hi) + 0x8000u;
    return __builtin_amdgcn_perm(uh, ul, 0x07060302);
}

// ---- pack (Wa + sgn*Wb)[K][N] fp32 -> bf16 MFMA A-fragments of W^T ----
template<int K, int N>
__device__ inline void pack_w2_dev(const float* __restrict__ Wa, const float* __restrict__ Wb,
                                   float sgn, u16* __restrict__ out, int blk) {
    constexpr int NC = K / 16;
    int idx = blk * 256 + threadIdx.x;
    int j    = idx & 7;
    int lane = (idx >> 3) & 63;
    int rest = idx >> 9;
    int c  = rest % NC;
    int mt = rest / NC;
    int k = c * 16 + ((lane >> 5) << 3) + j;
    int n = mt * 32 + (lane & 31);
    out[idx] = f2bf(Wa[k * N + n] + sgn * Wb[k * N + n]);
}
// ---- alpha pack: alpha[T][N] -> bf16 in transposed-C/D epilogue order ----
template<int NTOT>
__device__ inline void pack_a_dev(const float* __restrict__ A, u16* __restrict__ out, int blk) {
    constexpr int MTOT = NTOT / 32;
    int idx = blk * 256 + threadIdx.x;
    int reg  = idx & 15;
    int lane = (idx >> 4) & 63;
    int rest = idx >> 10;
    int mt = rest % MTOT;
    int g  = rest / MTOT;
    int t  = (g >> 1) * 64 + (g & 1) * 32 + (lane & 31);
    int n  = mt * 32 + (reg & 3) + ((reg >> 2) << 3) + ((lane >> 5) << 2);
    out[idx] = (t < TT) ? f2bf(A[t * NTOT + n]) : (u16)0;
}

__global__ void pack_all(const float* __restrict__ W1, const float* __restrict__ W2,
                         const float* __restrict__ W3, const float* __restrict__ a1,
                         const float* __restrict__ a2, const float* __restrict__ a3,
                         u16* W1kdp, u16* W1pp, u16* W1qdp, u16* W2p, u16* W3p,
                         u16* A1p, u16* A2p, u16* A3p) {
    int blk = blockIdx.x;
    const float* W1q = W1;
    const float* W1k = W1 + 64 * H1C;
    const float* W1d = W1 + 128 * H1C;
    const float* W1p = W1 + 192 * H1C;
    if      (blk < 64)  pack_w2_dev<64, H1C>(W1k, W1d, -1.f, W1kdp, blk);
    else if (blk < 128) pack_w2_dev<64, H1C>(W1p, W1p,  0.f, W1pp,  blk - 64);
    else if (blk < 192) pack_w2_dev<64, H1C>(W1q, W1d,  1.f, W1qdp, blk - 128);
    else if (blk < 320) pack_w2_dev<H1C, H2C>(W2, W2,   0.f, W2p,   blk - 192);
    else if (blk < 352) pack_w2_dev<H2C, H3C>(W3, W3,   0.f, W3p,   blk - 320);
    else if (blk < 608) pack_a_dev<H1C>(a1, A1p, blk - 352);
    else if (blk < 736) pack_a_dev<H2C>(a2, A2p, blk - 608);
    else                pack_a_dev<H3C>(a3, A3p, blk - 736);
}

// Streamed layer (transposed): D[n][t] = sum_k W^T[n][k] X^T[k][t].
// Weights 2-frag ping-pong from L2 (no big arrays). TTN = 1.
template<int NC, int NTOT, int IN_S, int OUT_S>
__device__ __attribute__((always_inline)) inline
void layer_s(const u16* Xb, u16* Y, const u16* __restrict__ Wp,
             const float* __restrict__ bias, const u16* __restrict__ Ap,
             int mt, int tt, int lane, int mb) {
    constexpr int MTOT = NTOT / 32;
    const int tl   = lane & 31;
    const int kq   = (lane >> 5) << 3;
    const int hsel = (lane >> 5) << 2;
    const u16* wp = Wp + ((size_t)(mt * NC) * 64 + lane) * 8;
    const u16* xb = Xb + (tt * 32 + tl) * IN_S + kq;

    // alpha prefetch (L2-hot, consumed in epilogue)
    const u16* ap = Ap + (((size_t)((mb * 2 + tt) * MTOT + mt) * 64 + lane) << 4);
    u16x8 av0 = *reinterpret_cast<const u16x8*>(ap);
    u16x8 av1 = *reinterpret_cast<const u16x8*>(ap + 8);

    floatx16 acc;
#pragma unroll
    for (int i = 0; i < 16; ++i) acc[i] = 0.f;

    bf16x8 wa0, wa1, wb0, wb1;
    wa0 = *reinterpret_cast<const bf16x8*>(wp);
    wa1 = *reinterpret_cast<const bf16x8*>(wp + 512);
#pragma unroll
    for (int g = 0; g < NC; g += 4) {
        wb0 = *reinterpret_cast<const bf16x8*>(wp + (size_t)(g + 2) * 512);
        wb1 = *reinterpret_cast<const bf16x8*>(wp + (size_t)(g + 3) * 512);
        acc = __builtin_amdgcn_mfma_f32_32x32x16_bf16(
            wa0, *reinterpret_cast<const bf16x8*>(xb + g * 16), acc, 0, 0, 0);
        acc = __builtin_amdgcn_mfma_f32_32x32x16_bf16(
            wa1, *reinterpret_cast<const bf16x8*>(xb + (g + 1) * 16), acc, 0, 0, 0);
        if (g + 4 < NC) {
            wa0 = *reinterpret_cast<const bf16x8*>(wp + (size_t)(g + 4) * 512);
            wa1 = *reinterpret_cast<const bf16x8*>(wp + (size_t)(g + 5) * 512);
        }
        acc = __builtin_amdgcn_mfma_f32_32x32x16_bf16(
            wb0, *reinterpret_cast<const bf16x8*>(xb + (g + 2) * 16), acc, 0, 0, 0);
        acc = __builtin_amdgcn_mfma_f32_32x32x16_bf16(
            wb1, *reinterpret_cast<const bf16x8*>(xb + (g + 3) * 16), acc, 0, 0, 0);
    }

    u16* yrow = Y + (tt * 32 + tl) * OUT_S + mt * 32 + hsel;
#pragma unroll
    for (int q = 0; q < 4; ++q) {
        f32x4 bv = *reinterpret_cast<const f32x4*>(bias + mt * 32 + q * 8 + hsel);
        float p[4];
#pragma unroll
        for (int i = 0; i < 4; ++i) {
            const int r = q * 4 + i;
            float v = acc[r] + bv[i];
            float al = bf2f(r < 8 ? av0[r] : av1[r - 8]);
            p[i] = fmaxf(v, 0.f) + al * fminf(v, 0.f);
        }
        u32x2 pw = { pkbf(p[0], p[1]), pkbf(p[2], p[3]) };
        *reinterpret_cast<u32x2*>(yrow + q * 8) = pw;
    }
}

__device__ inline void load_k(const float* __restrict__ Kin, int b, int t, int c0,
                              f32x4& a, f32x4& c) {
    if (t < TT) {
        const f32x4* p = reinterpret_cast<const f32x4*>(Kin + ((size_t)b * TT + t) * DD + c0);
        a = __builtin_nontemporal_load(p);
        c = __builtin_nontemporal_load(p + 1);
    } else {
        a = f32x4{0.f, 0.f, 0.f, 0.f};
        c = f32x4{0.f, 0.f, 0.f, 0.f};
    }
}

__global__ __launch_bounds__(512, 4)
void attn_pool_kernel(const float* __restrict__ Q, const float* __restrict__ Kin,
                      const u16* __restrict__ W1kdp, const u16* __restrict__ W1pp,
                      const u16* __restrict__ W1qdp, const float* __restrict__ b1,
                      const u16* __restrict__ A1p,
                      const u16* __restrict__ W2p, const float* __restrict__ b2,
                      const u16* __restrict__ A2p,
                      const u16* __restrict__ W3p, const float* __restrict__ b3,
                      const u16* __restrict__ A3p,
                      const float* __restrict__ Wl, const float* __restrict__ bl,
                      float* __restrict__ Out) {
    __shared__ __align__(16) u16 k_sh[64 * 72];     // bf16 k rows (layer1 B + pooling)
    __shared__ __align__(16) u16 h1s[64 * 264];     // h1; h3 overlays cols 0..63 later
    __shared__ __align__(16) u16 h2s[64 * 136];
    __shared__ float q_sh[64];
    __shared__ float k0_sh[64];
    __shared__ float pool_red[8][64];

    const int tid  = threadIdx.x;
    const int lane = tid & 63;
    const int w    = tid >> 6;          // 0..7
    const int b    = blockIdx.x;
    const int r    = tid >> 3;          // staging row 0..63
    const int c0   = (tid & 7) << 3;    // staging col group
    const int tl   = lane & 31;
    const int kq   = (lane >> 5) << 3;
    const int hsel = (lane >> 5) << 2;

    if (tid < 16) {
        reinterpret_cast<f32x4*>(q_sh)[tid] =
            reinterpret_cast<const f32x4*>(Q + (size_t)b * DD)[tid];
    }
    const float bl0 = bl[0];

    f32x4 kc0, kc1, kn0, kn1;
    load_k(Kin, b, r, c0, kc0, kc1);
    __syncthreads();                    // q_sh ready

    // ---- per-batch fold: M = (W1k - W1d) + W1p * q[f];  bias1 = b1 + (W1q+W1d)^T q
    bf16x8 mf[4];                       // persistent, 16 VGPRs
    floatx16 bias1;                     // persistent, 16 regs
    {
        const size_t fo = ((size_t)(w * 4) * 64 + lane) * 8;
        floatx16 accb;
#pragma unroll
        for (int i = 0; i < 16; ++i) accb[i] = 0.f;
#pragma unroll
        for (int c = 0; c < 4; ++c) {
            u16x8 kd = *reinterpret_cast<const u16x8*>(W1kdp + fo + (size_t)c * 512);
            u16x8 pf = *reinterpret_cast<const u16x8*>(W1pp  + fo + (size_t)c * 512);
            bf16x8 qd = *reinterpret_cast<const bf16x8*>(W1qdp + fo + (size_t)c * 512);
            f32x4 qa = *reinterpret_cast<const f32x4*>(&q_sh[c * 16 + kq]);
            f32x4 qb = *reinterpret_cast<const f32x4*>(&q_sh[c * 16 + kq + 4]);
            u32x4 qpack = { pkbf(qa[0], qa[1]), pkbf(qa[2], qa[3]),
                            pkbf(qb[0], qb[1]), pkbf(qb[2], qb[3]) };
            bf16x8 qf = __builtin_bit_cast(bf16x8, qpack);
            accb = __builtin_amdgcn_mfma_f32_32x32x16_bf16(qd, qf, accb, 0, 0, 0);
            float mv[8];
#pragma unroll
            for (int j = 0; j < 4; ++j) mv[j]     = bf2f(kd[j])     + bf2f(pf[j])     * qa[j];
#pragma unroll
            for (int j = 0; j < 4; ++j) mv[4 + j] = bf2f(kd[4 + j]) + bf2f(pf[4 + j]) * qb[j];
            u32x4 mpack = { pkbf(mv[0], mv[1]), pkbf(mv[2], mv[3]),
                            pkbf(mv[4], mv[5]), pkbf(mv[6], mv[7]) };
            mf[c] = __builtin_bit_cast(bf16x8, mpack);
        }
        // every lane's acc holds the full matvec (q-frag replicated) -> bias per lane cols
#pragma unroll
        for (int q = 0; q < 4; ++q) {
            f32x4 bv = *reinterpret_cast<const f32x4*>(b1 + w * 32 + q * 8 + hsel);
#pragma unroll
            for (int i = 0; i < 4; ++i) bias1[q * 4 + i] = accb[q * 4 + i] + bv[i];
        }
    }

    float pacc = 0.f;

#pragma unroll 1
    for (int mb = 0; mb < 4; ++mb) {
        const int t0 = mb * 64;

        // ---- stage k (bf16) only
        {
            u32x4 uk = { pkbf(kc0[0], kc0[1]), pkbf(kc0[2], kc0[3]),
                         pkbf(kc1[0], kc1[1]), pkbf(kc1[2], kc1[3]) };
            *reinterpret_cast<u32x4*>(k_sh + r * 72 + c0) = uk;
            if (c0 == 0) k0_sh[r] = kc0[0];
        }
        if (mb < 3) load_k(Kin, b, t0 + 64 + r, c0, kn0, kn1);
        __syncthreads();                                            // (1) k ready

        // ---- layer1: K=64 with folded M (registers); wave w -> cols w*32..
#pragma unroll
        for (int tt = 0; tt < 2; ++tt) {
            const u16* ap = A1p + (((size_t)((mb * 2 + tt) * 8 + w) * 64 + lane) << 4);
            u16x8 av0 = *reinterpret_cast<const u16x8*>(ap);
            u16x8 av1 = *reinterpret_cast<const u16x8*>(ap + 8);
            floatx16 acc;
#pragma unroll
            for (int i = 0; i < 16; ++i) acc[i] = bias1[i];
            const u16* xb = k_sh + (tt * 32 + tl) * 72 + kq;
#pragma unroll
            for (int c = 0; c < 4; ++c) {
                acc = __builtin_amdgcn_mfma_f32_32x32x16_bf16(
                    mf[c], *reinterpret_cast<const bf16x8*>(xb + c * 16), acc, 0, 0, 0);
            }
            u16* yrow = h1s + (tt * 32 + tl) * 264 + w * 32 + hsel;
#pragma unroll
            for (int q = 0; q < 4; ++q) {
                float p[4];
#pragma unroll
                for (int i = 0; i < 4; ++i) {
                    const int rr = q * 4 + i;
                    float v = acc[rr];
                    float al = bf2f(rr < 8 ? av0[rr] : av1[rr - 8]);
                    p[i] = fmaxf(v, 0.f) + al * fminf(v, 0.f);
                }
                u32x2 pw = { pkbf(p[0], p[1]), pkbf(p[2], p[3]) };
                *reinterpret_cast<u32x2*>(yrow + q * 8) = pw;
            }
        }
        __syncthreads();                                            // (2) h1 ready

        // ---- layer2: h1 @ W2 -> h2 (streamed)
        layer_s<16, H2C, 264, 136>(h1s, h2s, W2p, b2, A2p, w & 3, w >> 2, lane, mb);
        __syncthreads();                                            // (3) h2 ready

        // ---- layer3: h2 @ W3 -> h3 (h1s cols 0..63)
        if (w < 4)
            layer_s<8, H3C, 136, 264>(h2s, h1s, W3p, b3, A3p, w & 1, w >> 1, lane, mb);
        __syncthreads();                                            // (4) h3 ready

        // ---- score + pooling fused
        {
            const int sm = tid >> 3;
            const int p  = tid & 7;
            u16x8 hv = *reinterpret_cast<const u16x8*>(h1s + sm * 264 + p * 8);
            const f32x4 wl0 = *reinterpret_cast<const f32x4*>(Wl + p * 8);
            const f32x4 wl1 = *reinterpret_cast<const f32x4*>(Wl + p * 8 + 4);
            float s = 0.f;
#pragma unroll
            for (int i = 0; i < 4; ++i) s += bf2f(hv[i]) * wl0[i];
#pragma unroll
            for (int i = 0; i < 4; ++i) s += bf2f(hv[4 + i]) * wl1[i];
            s += __shfl_xor(s, 1);
            s += __shfl_xor(s, 2);
            s += __shfl_xor(s, 4);
            const int t = t0 + sm;
            float sc = s + bl0;
            if (t >= TT || k0_sh[sm] == 0.f) sc = 0.f;
#pragma unroll
            for (int i = 0; i < 8; ++i) {
                float si = __shfl(sc, 8 * i);
                pacc += si * bf2f(k_sh[(w * 8 + i) * 72 + lane]);
            }
        }
        __syncthreads();                                            // (5) k_sh reusable
        kc0 = kn0; kc1 = kn1;
    }

    pool_red[w][lane] = pacc;
    __syncthreads();
    if (tid < 64) {
        float s = 0.f;
#pragma unroll
        for (int i = 0; i < 8; ++i) s += pool_red[i][tid];
        Out[(size_t)b * DD + tid] = s;
    }
}

extern "C" void kernel_launch(void* const* d_in, const int* in_sizes, int n_in,
                              void* d_out, int out_size, void* d_ws, size_t ws_size,
                              hipStream_t stream) {
    (void)in_sizes; (void)n_in; (void)out_size; (void)ws_size;
    const float* Q  = (const float*)d_in[0];
    const float* Kk = (const float*)d_in[1];
    const float* W1 = (const float*)d_in[2];
    const float* b1 = (const float*)d_in[3];
    const float* a1 = (const float*)d_in[4];
    const float* W2 = (const float*)d_in[5];
    const float* b2 = (const float*)d_in[6];
    const float* a2 = (const float*)d_in[7];
    const float* W3 = (const float*)d_in[8];
    const float* b3 = (const float*)d_in[9];
    const float* a3 = (const float*)d_in[10];
    const float* Wl = (const float*)d_in[11];
    const float* bl = (const float*)d_in[12];
    float* Out = (float*)d_out;

    u16* ws    = (u16*)d_ws;
    u16* W1kdp = ws;                       // 16384 bf16
    u16* W1pp  = W1kdp + 16384;            // 16384
    u16* W1qdp = W1pp  + 16384;            // 16384
    u16* W2p   = W1qdp + 16384;            // 32768
    u16* W3p   = W2p   + 32768;            //  8192
    u16* A1p   = W3p   + 8192;             // 65536
    u16* A2p   = A1p   + 65536;            // 32768
    u16* A3p   = A2p   + 32768;            // 16384

    hipLaunchKernelGGL(pack_all, dim3(800), dim3(256), 0, stream,
                       W1, W2, W3, a1, a2, a3,
                       W1kdp, W1pp, W1qdp, W2p, W3p, A1p, A2p, A3p);
    hipLaunchKernelGGL(attn_pool_kernel, dim3(BB), dim3(512), 0, stream,
                       Q, Kk, W1kdp, W1pp, W1qdp, b1, A1p, W2p, b2, A2p,
                       W3p, b3, A3p, Wl, bl, Out);
}

// Round 6
// 306.595 us; speedup vs baseline: 2.1816x; 1.6090x over previous
//
#include <hip/hip_runtime.h>
#include <stdint.h>

#define BB 2048
#define TT 200
#define DD 64
#define FF 256   // 4*D
#define H1C 256
#define H2C 128
#define H3C 64

typedef __bf16 bf16x8 __attribute__((ext_vector_type(8)));
typedef float floatx16 __attribute__((ext_vector_type(16)));
typedef float f32x4 __attribute__((ext_vector_type(4)));
typedef uint32_t u32x4 __attribute__((ext_vector_type(4)));
typedef uint32_t u32x2 __attribute__((ext_vector_type(2)));
typedef unsigned short u16;
typedef u16 u16x8 __attribute__((ext_vector_type(8)));

__device__ inline u16 f2bf(float f) {
    uint32_t u = __builtin_bit_cast(uint32_t, f) + 0x8000u;
    return (u16)(u >> 16);
}
__device__ inline float bf2f(u16 h) {
    uint32_t u = ((uint32_t)h) << 16;
    return __builtin_bit_cast(float, u);
}
__device__ inline uint32_t pkbf(float lo, float hi) {
    uint32_t ul = __builtin_bit_cast(uint32_t, lo) + 0x8000u;
    uint32_t uh = __builtin_bit_cast(uint32_t, hi) + 0x8000u;
    return __builtin_amdgcn_perm(uh, ul, 0x07060302);
}

// ---- pack (Wa + sgn*Wb)[K][N] fp32 -> bf16 MFMA A-fragments of W^T ----
template<int K, int N>
__device__ inline void pack_w2_dev(const float* __restrict__ Wa, const float* __restrict__ Wb,
                                   float sgn, u16* __restrict__ out, int blk) {
    constexpr int NC = K / 16;
    int idx = blk * 256 + threadIdx.x;
    int j    = idx & 7;
    int lane = (idx >> 3) & 63;
    int rest = idx >> 9;
    int c  = rest % NC;
    int mt = rest / NC;
    int k = c * 16 + ((lane >> 5) << 3) + j;
    int n = mt * 32 + (lane & 31);
    out[idx] = f2bf(Wa[k * N + n] + sgn * Wb[k * N + n]);
}
// ---- alpha pack: alpha[T][N] -> bf16 in transposed-C/D epilogue order ----
template<int NTOT>
__device__ inline void pack_a_dev(const float* __restrict__ A, u16* __restrict__ out, int blk) {
    constexpr int MTOT = NTOT / 32;
    int idx = blk * 256 + threadIdx.x;
    int reg  = idx & 15;
    int lane = (idx >> 4) & 63;
    int rest = idx >> 10;
    int mt = rest % MTOT;
    int g  = rest / MTOT;
    int t  = (g >> 1) * 64 + (g & 1) * 32 + (lane & 31);
    int n  = mt * 32 + (reg & 3) + ((reg >> 2) << 3) + ((lane >> 5) << 2);
    out[idx] = (t < TT) ? f2bf(A[t * NTOT + n]) : (u16)0;
}

__global__ void pack_all(const float* __restrict__ W1, const float* __restrict__ W2,
                         const float* __restrict__ W3, const float* __restrict__ a1,
                         const float* __restrict__ a2, const float* __restrict__ a3,
                         u16* W1kdp, u16* W1pp, u16* W1qdp, u16* W2p, u16* W3p,
                         u16* A1p, u16* A2p, u16* A3p) {
    int blk = blockIdx.x;
    const float* W1q = W1;
    const float* W1k = W1 + 64 * H1C;
    const float* W1d = W1 + 128 * H1C;
    const float* W1p = W1 + 192 * H1C;
    if      (blk < 64)  pack_w2_dev<64, H1C>(W1k, W1d, -1.f, W1kdp, blk);
    else if (blk < 128) pack_w2_dev<64, H1C>(W1p, W1p,  0.f, W1pp,  blk - 64);
    else if (blk < 192) pack_w2_dev<64, H1C>(W1q, W1d,  1.f, W1qdp, blk - 128);
    else if (blk < 320) pack_w2_dev<H1C, H2C>(W2, W2,   0.f, W2p,   blk - 192);
    else if (blk < 352) pack_w2_dev<H2C, H3C>(W3, W3,   0.f, W3p,   blk - 320);
    else if (blk < 608) pack_a_dev<H1C>(a1, A1p, blk - 352);
    else if (blk < 736) pack_a_dev<H2C>(a2, A2p, blk - 608);
    else                pack_a_dev<H3C>(a3, A3p, blk - 736);
}

// PReLU + bf16-pack + swizzled store of one lane's 16-reg C column-quads.
// yrow = Y + row*STRIDE + mt*32 + hl*4 ; quad q lands at group (q^S).
__device__ __attribute__((always_inline)) inline
void store_tile(u16* yrow, int S, const floatx16& acc, u16x8 av0, u16x8 av1) {
#pragma unroll
    for (int q = 0; q < 4; ++q) {
        float p[4];
#pragma unroll
        for (int i = 0; i < 4; ++i) {
            const int r = q * 4 + i;
            float v = acc[r];
            float al = bf2f(r < 8 ? av0[r] : av1[r - 8]);
            p[i] = fmaxf(v, 0.f) + al * fminf(v, 0.f);
        }
        u32x2 pw = { pkbf(p[0], p[1]), pkbf(p[2], p[3]) };
        *reinterpret_cast<u32x2*>(yrow + ((q ^ S) << 3)) = pw;
    }
}

__device__ inline void load_k4(const float* __restrict__ Kin, int b, int t, int c0,
                               f32x4* kk) {
    if (t < TT) {
        const f32x4* p = reinterpret_cast<const f32x4*>(Kin + ((size_t)b * TT + t) * DD + c0);
#pragma unroll
        for (int i = 0; i < 4; ++i) kk[i] = __builtin_nontemporal_load(p + i);
    } else {
#pragma unroll
        for (int i = 0; i < 4; ++i) kk[i] = f32x4{0.f, 0.f, 0.f, 0.f};
    }
}

__global__ __launch_bounds__(256, 2)
void attn_pool_kernel(const float* __restrict__ Q, const float* __restrict__ Kin,
                      const u16* __restrict__ W1kdp, const u16* __restrict__ W1pp,
                      const u16* __restrict__ W1qdp, const float* __restrict__ b1,
                      const u16* __restrict__ A1p,
                      const u16* __restrict__ W2p, const float* __restrict__ b2,
                      const u16* __restrict__ A2p,
                      const u16* __restrict__ W3p, const float* __restrict__ b3,
                      const u16* __restrict__ A3p,
                      const float* __restrict__ Wl, const float* __restrict__ bl,
                      float* __restrict__ Out) {
    __shared__ __align__(16) u16 k_sh[64 * 72];     // bf16 k (layer1 B + pooling)
    __shared__ __align__(16) u16 h1s[64 * 264];     // h1; h3 overlays cols 0..63
    __shared__ __align__(16) u16 h2s[64 * 136];
    __shared__ float q_sh[64];
    __shared__ float k0_sh[64];
    __shared__ float fb1_sh[H1C];                   // folded layer1 bias (per batch)
    __shared__ float pool_red[4][64];

    const int tid  = threadIdx.x;
    const int lane = tid & 63;
    const int w    = tid >> 6;          // 0..3
    const int b    = blockIdx.x;
    const int tl   = lane & 31;
    const int hl   = lane >> 5;
    const int kq   = hl << 3;
    const int hsel = hl << 2;
    const int S    = (tl >> 3) & 1;     // write-swizzle bit
    const int r    = tid >> 2;          // staging row 0..63
    const int c0   = (tid & 3) << 4;    // staging col group (16 cols)

    if (tid < 16) {
        reinterpret_cast<f32x4*>(q_sh)[tid] =
            reinterpret_cast<const f32x4*>(Q + (size_t)b * DD)[tid];
    }
    const float bl0 = bl[0];

    f32x4 kn[4];
    load_k4(Kin, b, r, c0, kn);
    __syncthreads();                    // q_sh ready

    // ---- per-batch fold: M = (W1k-W1d) + W1p*q ; fb1 = b1 + (W1q+W1d)^T q
    bf16x8 mf[2][4];                    // 32 VGPRs persistent
    {
#pragma unroll
        for (int s = 0; s < 2; ++s) {
            const int mt = w + 4 * s;
            const size_t fo = ((size_t)(mt * 4) * 64 + lane) * 8;
            floatx16 accb;
#pragma unroll
            for (int i = 0; i < 16; ++i) accb[i] = 0.f;
#pragma unroll
            for (int c = 0; c < 4; ++c) {
                u16x8 kd = *reinterpret_cast<const u16x8*>(W1kdp + fo + (size_t)c * 512);
                u16x8 pf = *reinterpret_cast<const u16x8*>(W1pp  + fo + (size_t)c * 512);
                bf16x8 qd = *reinterpret_cast<const bf16x8*>(W1qdp + fo + (size_t)c * 512);
                f32x4 qa = *reinterpret_cast<const f32x4*>(&q_sh[c * 16 + kq]);
                f32x4 qb = *reinterpret_cast<const f32x4*>(&q_sh[c * 16 + kq + 4]);
                u32x4 qpack = { pkbf(qa[0], qa[1]), pkbf(qa[2], qa[3]),
                                pkbf(qb[0], qb[1]), pkbf(qb[2], qb[3]) };
                bf16x8 qf = __builtin_bit_cast(bf16x8, qpack);
                accb = __builtin_amdgcn_mfma_f32_32x32x16_bf16(qd, qf, accb, 0, 0, 0);
                float mv[8];
#pragma unroll
                for (int j = 0; j < 4; ++j) mv[j]     = bf2f(kd[j])     + bf2f(pf[j])     * qa[j];
#pragma unroll
                for (int j = 0; j < 4; ++j) mv[4 + j] = bf2f(kd[4 + j]) + bf2f(pf[4 + j]) * qb[j];
                u32x4 mpack = { pkbf(mv[0], mv[1]), pkbf(mv[2], mv[3]),
                                pkbf(mv[4], mv[5]), pkbf(mv[6], mv[7]) };
                mf[s][c] = __builtin_bit_cast(bf16x8, mpack);
            }
            if (tl == 0) {              // accb replicated across tl; one writer
#pragma unroll
                for (int q = 0; q < 4; ++q) {
                    f32x4 bv = *reinterpret_cast<const f32x4*>(b1 + mt * 32 + q * 8 + hsel);
#pragma unroll
                    for (int i = 0; i < 4; ++i)
                        fb1_sh[mt * 32 + q * 8 + hsel + i] = accb[q * 4 + i] + bv[i];
                }
            }
        }
    }

    // ---- persistent W2 fragments (mt = w), reused across both t-tiles & all mb
    bf16x8 wf2[16];                     // 64 VGPRs
    {
        const u16* p2 = W2p + (size_t)(w * 16) * 512 + lane * 8;
#pragma unroll
        for (int c = 0; c < 16; ++c)
            wf2[c] = *reinterpret_cast<const bf16x8*>(p2 + (size_t)c * 512);
    }
    // ---- biases for layers 2/3 pre-staged as acc-init vectors
    const int mt3 = w & 1, tt3 = w >> 1;
    floatx16 bq2, bq3;
#pragma unroll
    for (int q = 0; q < 4; ++q) {
        f32x4 v2 = *reinterpret_cast<const f32x4*>(b2 + w * 32 + q * 8 + hsel);
        f32x4 v3 = *reinterpret_cast<const f32x4*>(b3 + mt3 * 32 + q * 8 + hsel);
#pragma unroll
        for (int i = 0; i < 4; ++i) { bq2[q * 4 + i] = v2[i]; bq3[q * 4 + i] = v3[i]; }
    }

    float pacc = 0.f;

#pragma unroll 1
    for (int mb = 0; mb < 4; ++mb) {
        const int t0 = mb * 64;

        // ---- stage k (bf16) from prefetched registers
        {
            f32x4 kc[4] = { kn[0], kn[1], kn[2], kn[3] };
            if (mb < 3) load_k4(Kin, b, t0 + 64 + r, c0, kn);
            u32x4 ua = { pkbf(kc[0][0], kc[0][1]), pkbf(kc[0][2], kc[0][3]),
                         pkbf(kc[1][0], kc[1][1]), pkbf(kc[1][2], kc[1][3]) };
            u32x4 ub = { pkbf(kc[2][0], kc[2][1]), pkbf(kc[2][2], kc[2][3]),
                         pkbf(kc[3][0], kc[3][1]), pkbf(kc[3][2], kc[3][3]) };
            *reinterpret_cast<u32x4*>(k_sh + r * 72 + c0)     = ua;
            *reinterpret_cast<u32x4*>(k_sh + r * 72 + c0 + 8) = ub;
            if (c0 == 0) k0_sh[r] = kc[0][0];
        }
        __syncthreads();                                            // (1) k ready

        // ---- layer1: K=64 folded-M; wave w -> mt = w, w+4; both t-tiles
#pragma unroll
        for (int s = 0; s < 2; ++s) {
            const int mt = w + 4 * s;
#pragma unroll
            for (int tt = 0; tt < 2; ++tt) {
                const u16* ap = A1p + (((size_t)((mb * 2 + tt) * 8 + mt) * 64 + lane) << 4);
                u16x8 av0 = *reinterpret_cast<const u16x8*>(ap);
                u16x8 av1 = *reinterpret_cast<const u16x8*>(ap + 8);
                floatx16 acc;
#pragma unroll
                for (int q = 0; q < 4; ++q) {
                    f32x4 bv = *reinterpret_cast<const f32x4*>(&fb1_sh[mt * 32 + q * 8 + hsel]);
#pragma unroll
                    for (int i = 0; i < 4; ++i) acc[q * 4 + i] = bv[i];
                }
                const u16* xb = k_sh + (tt * 32 + tl) * 72 + kq;
#pragma unroll
                for (int c = 0; c < 4; ++c)
                    acc = __builtin_amdgcn_mfma_f32_32x32x16_bf16(
                        mf[s][c], *reinterpret_cast<const bf16x8*>(xb + c * 16), acc, 0, 0, 0);
                store_tile(h1s + (tt * 32 + tl) * 264 + mt * 32 + hsel, S, acc, av0, av1);
            }
        }
        __syncthreads();                                            // (2) h1 ready

        // ---- layer2: persistent wf2 (mt=w), both t-tiles
#pragma unroll
        for (int tt = 0; tt < 2; ++tt) {
            const u16* ap = A2p + (((size_t)((mb * 2 + tt) * 4 + w) * 64 + lane) << 4);
            u16x8 av0 = *reinterpret_cast<const u16x8*>(ap);
            u16x8 av1 = *reinterpret_cast<const u16x8*>(ap + 8);
            floatx16 acc = bq2;
            const u16* xb = h1s + (tt * 32 + tl) * 264 + ((hl ^ S) << 3);
#pragma unroll
            for (int c = 0; c < 16; ++c)
                acc = __builtin_amdgcn_mfma_f32_32x32x16_bf16(
                    wf2[c], *reinterpret_cast<const bf16x8*>(xb + c * 16), acc, 0, 0, 0);
            store_tile(h2s + (tt * 32 + tl) * 136 + w * 32 + hsel, S, acc, av0, av1);
        }
        __syncthreads();                                            // (3) h2 ready

        // ---- layer3: wave -> (tt3, mt3); weights streamed (L2-hot)
        {
            const u16* ap = A3p + (((size_t)((mb * 2 + tt3) * 2 + mt3) * 64 + lane) << 4);
            u16x8 av0 = *reinterpret_cast<const u16x8*>(ap);
            u16x8 av1 = *reinterpret_cast<const u16x8*>(ap + 8);
            const u16* wp3 = W3p + (size_t)(mt3 * 8) * 512 + lane * 8;
            floatx16 acc = bq3;
            const u16* xb = h2s + (tt3 * 32 + tl) * 136 + ((hl ^ S) << 3);
#pragma unroll
            for (int c = 0; c < 8; ++c)
                acc = __builtin_amdgcn_mfma_f32_32x32x16_bf16(
                    *reinterpret_cast<const bf16x8*>(wp3 + (size_t)c * 512),
                    *reinterpret_cast<const bf16x8*>(xb + c * 16), acc, 0, 0, 0);
            store_tile(h1s + (tt3 * 32 + tl) * 264 + mt3 * 32 + hsel, S, acc, av0, av1);
        }
        __syncthreads();                                            // (4) h3 ready

        // ---- score (row = tid>>2, 4-lane split) + pooling fused
        {
            const int sr  = tid >> 2;
            const int p   = tid & 3;
            const int Ssc = (sr >> 3) & 1;
            const u16* hrow = h1s + sr * 264 + p * 16;
            u16x8 hv0 = *reinterpret_cast<const u16x8*>(hrow + 8 * Ssc);
            u16x8 hv1 = *reinterpret_cast<const u16x8*>(hrow + 8 * (1 - Ssc));
            float s = 0.f;
#pragma unroll
            for (int i = 0; i < 8; ++i) s += bf2f(hv0[i]) * Wl[p * 16 + i];
#pragma unroll
            for (int i = 0; i < 8; ++i) s += bf2f(hv1[i]) * Wl[p * 16 + 8 + i];
            s += __shfl_xor(s, 1);
            s += __shfl_xor(s, 2);
            const int t = t0 + sr;
            float sc = s + bl0;
            if (t >= TT || k0_sh[sr] == 0.f) sc = 0.f;
            // wave w owns rows w*16 .. w*16+15 (its own lanes' rows)
#pragma unroll
            for (int i = 0; i < 16; ++i) {
                float si = __shfl(sc, 4 * i);
                pacc += si * bf2f(k_sh[(w * 16 + i) * 72 + lane]);
            }
        }
        __syncthreads();                                            // (5) LDS reusable
    }

    pool_red[w][lane] = pacc;
    __syncthreads();
    if (tid < 64) {
        Out[(size_t)b * DD + tid] = pool_red[0][tid] + pool_red[1][tid]
                                  + pool_red[2][tid] + pool_red[3][tid];
    }
}

extern "C" void kernel_launch(void* const* d_in, const int* in_sizes, int n_in,
                              void* d_out, int out_size, void* d_ws, size_t ws_size,
                              hipStream_t stream) {
    (void)in_sizes; (void)n_in; (void)out_size; (void)ws_size;
    const float* Q  = (const float*)d_in[0];
    const float* Kk = (const float*)d_in[1];
    const float* W1 = (const float*)d_in[2];
    const float* b1 = (const float*)d_in[3];
    const float* a1 = (const float*)d_in[4];
    const float* W2 = (const float*)d_in[5];
    const float* b2 = (const float*)d_in[6];
    const float* a2 = (const float*)d_in[7];
    const float* W3 = (const float*)d_in[8];
    const float* b3 = (const float*)d_in[9];
    const float* a3 = (const float*)d_in[10];
    const float* Wl = (const float*)d_in[11];
    const float* bl = (const float*)d_in[12];
    float* Out = (float*)d_out;

    u16* ws    = (u16*)d_ws;
    u16* W1kdp = ws;                       // 16384 bf16
    u16* W1pp  = W1kdp + 16384;            // 16384
    u16* W1qdp = W1pp  + 16384;            // 16384
    u16* W2p   = W1qdp + 16384;            // 32768
    u16* W3p   = W2p   + 32768;            //  8192
    u16* A1p   = W3p   + 8192;             // 65536
    u16* A2p   = A1p   + 65536;            // 32768
    u16* A3p   = A2p   + 32768;            // 16384

    hipLaunchKernelGGL(pack_all, dim3(800), dim3(256), 0, stream,
                       W1, W2, W3, a1, a2, a3,
                       W1kdp, W1pp, W1qdp, W2p, W3p, A1p, A2p, A3p);
    hipLaunchKernelGGL(attn_pool_kernel, dim3(BB), dim3(256), 0, stream,
                       Q, Kk, W1kdp, W1pp, W1qdp, b1, A1p, W2p, b2, A2p,
                       W3p, b3, A3p, Wl, bl, Out);
}